// Round 2
// baseline (4333.847 us; speedup 1.0000x reference)
//
#include <hip/hip_runtime.h>
#include <hip/hip_bf16.h>
#include <cstdint>
#include <cstddef>

// ---------------------------------------------------------------------------
// Types & helpers
// ---------------------------------------------------------------------------
typedef _Float16 f16x8_t __attribute__((ext_vector_type(8)));
typedef float    f32x4_t __attribute__((ext_vector_type(4)));
typedef unsigned short u16x8_t __attribute__((ext_vector_type(8)));
typedef unsigned short u16x4_t __attribute__((ext_vector_type(4)));

__device__ __forceinline__ unsigned short f2h(float f) {
    return __builtin_bit_cast(unsigned short, (_Float16)f);
}
__device__ __forceinline__ float h2f(unsigned short h) {
    return (float)__builtin_bit_cast(_Float16, h);
}
__device__ __forceinline__ f16x8_t load_h8(const unsigned short* p) {
    u16x8_t r = *(const u16x8_t*)p;
    return __builtin_bit_cast(f16x8_t, r);
}

// ---------------------------------------------------------------------------
// Problem constants
// ---------------------------------------------------------------------------
#define BATCH 16
#define CFULL 512
#define CMID  256
#define HW    3136   // 56*56
#define WDIM  56

// ---------------------------------------------------------------------------
// prep_tabs: top-k ranks + sigmoid scales + BN (a,b) constants + zero pad
//   bnab layout: [4][2][256] floats: q=0 bn31, 1 bn33, 2 bna1, 3 bna2
// ---------------------------------------------------------------------------
__global__ void prep_tabs(const float* __restrict__ cscore,
                          const float* __restrict__ bn31, const float* __restrict__ bn33,
                          const float* __restrict__ bna1, const float* __restrict__ bna2,
                          int* __restrict__ pos_tab, float* __restrict__ scale_tab,
                          float* __restrict__ bnab, unsigned short* __restrict__ zpad)
{
    __shared__ float s[1024];
    int t = threadIdx.x;
    s[t] = cscore[t];
    __syncthreads();
    float sj = s[t];
    int cnt = 0;
    for (int k = 0; k < 1024; ++k) {
        float sk = s[k];
        cnt += (sk > sj) || (sk == sj && k < t);
    }
    pos_tab[t]   = (cnt < 512) ? cnt : -1;
    scale_tab[t] = 1.0f / (1.0f + expf(-sj));

    if (t < 256) {
        const float* srcs[4] = {bn31, bn33, bna1, bna2};
        #pragma unroll
        for (int q = 0; q < 4; ++q) {
            const float* sp = srcs[q];
            float g = sp[t], b = sp[256 + t], m = sp[512 + t], v = sp[768 + t];
            float a = g * rsqrtf(v + 1e-5f);
            bnab[q * 512 + t]       = a;
            bnab[q * 512 + 256 + t] = b - m * a;
        }
    }
    if (t < 512) zpad[t] = 0;
}

// ---------------------------------------------------------------------------
// prep_weights: fp16 weights, fuse_weight folded in.
//   Wcat  [768][512]   rows 0..255 = w_1x1*fw1, 256..511 = w31*fw2, 512..767 = wa1*fw3
//   Wmain [256][9][512]; W33r [256][9][256]
// ---------------------------------------------------------------------------
__global__ void prep_weights(const float* __restrict__ w_main, const float* __restrict__ w_1x1,
                             const float* __restrict__ w31, const float* __restrict__ wa1,
                             const float* __restrict__ w33, const float* __restrict__ fw,
                             unsigned short* __restrict__ Wcat,
                             unsigned short* __restrict__ Wmain,
                             unsigned short* __restrict__ W33r)
{
    int i = blockIdx.x * 256 + threadIdx.x;
    if (i < 393216) {                         // Wcat: 768*512
        int row = i >> 9, c = i & 511;
        float v;
        if (row < 256)      v = w_1x1[row * 512 + c] * fw[1];
        else if (row < 512) v = w31[(row - 256) * 512 + c] * fw[2];
        else                v = wa1[(row - 512) * 512 + c] * fw[3];
        Wcat[i] = f2h(v);
    } else if (i < 393216 + 1179648) {        // Wmain: 256*9*512
        int j = i - 393216;
        int o = j / 4608, r = j % 4608, tap = r >> 9, c = r & 511;
        Wmain[j] = f2h(w_main[(size_t)(o * 512 + c) * 9 + tap] * fw[0]);
    } else if (i < 2162688) {                 // W33r: 256*9*256
        int j = i - 1572864;
        int o = j / 2304, r = j % 2304, tap = r >> 8, c = r & 255;
        W33r[j] = f2h(w33[(size_t)(o * 256 + c) * 9 + tap]);
    }
}

// ---------------------------------------------------------------------------
// transpose_x: NCHW f32 -> NHWC f16.  grid (49, 8, 16), block 256.
// ---------------------------------------------------------------------------
__global__ void transpose_x(const float* __restrict__ x, unsigned short* __restrict__ xt)
{
    __shared__ unsigned short tile[64][65];
    int t = threadIdx.x;
    int hw0 = blockIdx.x * 64, c0 = blockIdx.y * 64, b = blockIdx.z;
    const float* xb = x + ((size_t)b * CFULL + c0) * HW + hw0;
    int hwL = t & 63, cL = t >> 6;
    #pragma unroll
    for (int i = 0; i < 16; ++i) {
        int c = cL + i * 4;
        tile[c][hwL] = f2h(xb[(size_t)c * HW + hwL]);
    }
    __syncthreads();
    int c8 = (t & 7) * 8, hw = t >> 3;
    #pragma unroll
    for (int i = 0; i < 2; ++i) {
        int hh = hw + i * 32;
        u16x8_t v;
        #pragma unroll
        for (int j = 0; j < 8; ++j) v[j] = tile[c8 + j][hh];
        *(u16x8_t*)(xt + ((size_t)b * HW + hw0 + hh) * CFULL + c0 + c8) = v;
    }
}

// ---------------------------------------------------------------------------
// Kernel A: main 3x3 conv + fused 1x1x3 GEMM on x_nhwc.
//   1-D grid of 1792 blocks, XCD-pinned by batch:
//     xcd = id & 7; slot = id >> 3 (0..223); b = xcd + 8*(slot/112);
//     rem = slot % 112; ob = rem/14 (0..7); pb = rem%14.
//   ob 0-1: main 3x3 (256 out ch);  ob 2-7: fused 1x1 (768 out ch).
//   Block tile: 128 out-ch x 224 spatial, 4 waves (2x2), wave 64ch x 112sp.
// ---------------------------------------------------------------------------
__global__ __launch_bounds__(256, 4)
void convA(const unsigned short* __restrict__ X,
           const unsigned short* __restrict__ Wmain,
           const unsigned short* __restrict__ Wcat,
           const unsigned short* __restrict__ zpad,
           float* __restrict__ out,
           unsigned short* __restrict__ u_dst,
           unsigned short* __restrict__ avg_dst,
           const float* __restrict__ bnab,
           const int* __restrict__ pos_tab,
           const float* __restrict__ scale_tab)
{
    const int id = blockIdx.x;
    const int xcd = id & 7, slot = id >> 3;
    const int b = xcd + 8 * (slot / 112);
    const int rem = slot % 112;
    const int ob = rem / 14, pb = rem % 14;
    const bool is_main = (ob < 2);
    const int ntap = is_main ? 9 : 1;
    const int ob2 = ob - 2;                 // fused segment index source

    const int lane = threadIdx.x & 63;
    const int wid  = threadIdx.x >> 6;
    const int wm = wid >> 1, wn = wid & 1;
    const int lr = lane & 15;
    const int ko = (lane >> 4) * 8;

    const int o_wave = (is_main ? ob : ob2) * 128 + wm * 64;
    const int p_wave = pb * 224 + wn * 112;

    int h_[7], w_[7], p_[7];
    #pragma unroll
    for (int n = 0; n < 7; ++n) {
        int p = p_wave + n * 16 + lr;
        p_[n] = p; h_[n] = p / WDIM; w_[n] = p % WDIM;
    }

    const unsigned short* xb = X + (size_t)b * HW * CFULL;

    f32x4_t acc[4][7];
    #pragma unroll
    for (int m = 0; m < 4; ++m)
        #pragma unroll
        for (int n = 0; n < 7; ++n)
            acc[m][n] = (f32x4_t){0.f, 0.f, 0.f, 0.f};

    const int rowstride = ntap * CFULL;
    const unsigned short* wbase = is_main ? Wmain : Wcat;
    const unsigned short* ap[4];
    #pragma unroll
    for (int m = 0; m < 4; ++m)
        ap[m] = wbase + (size_t)(o_wave + m * 16 + lr) * rowstride + ko;

    for (int tap = 0; tap < ntap; ++tap) {
        const int dh = is_main ? (tap / 3 - 1) : 0;
        const int dw = is_main ? (tap % 3 - 1) : 0;
        const unsigned short* bp[7];
        #pragma unroll
        for (int n = 0; n < 7; ++n) {
            int hh = h_[n] + dh, ww = w_[n] + dw;
            bool v = ((unsigned)hh < (unsigned)WDIM) && ((unsigned)ww < (unsigned)WDIM);
            bp[n] = v ? (xb + (size_t)(hh * WDIM + ww) * CFULL + ko) : zpad;
        }
        #pragma unroll 4
        for (int kc = 0; kc < CFULL / 32; ++kc) {
            f16x8_t af[4], bfr[7];
            #pragma unroll
            for (int m = 0; m < 4; ++m) af[m] = load_h8(ap[m] + kc * 32);
            #pragma unroll
            for (int n = 0; n < 7; ++n) bfr[n] = load_h8(bp[n] + kc * 32);
            #pragma unroll
            for (int m = 0; m < 4; ++m)
                #pragma unroll
                for (int n = 0; n < 7; ++n)
                    acc[m][n] = __builtin_amdgcn_mfma_f32_16x16x32_f16(af[m], bfr[n], acc[m][n], 0, 0, 0);
        }
        #pragma unroll
        for (int m = 0; m < 4; ++m) ap[m] += CFULL;
    }

    // ---------------- epilogue ----------------
    const int fq = lane >> 4;
    const int seg = is_main ? 0 : (ob2 >> 1);          // fused: 0,1,2
    const bool bn_write = (!is_main) && (seg != 0);

    #pragma unroll
    for (int m = 0; m < 4; ++m) {
        const int orow = o_wave + m * 16 + fq * 4;
        #pragma unroll
        for (int n = 0; n < 7; ++n) {
            const int p = p_[n];
            f32x4_t v = acc[m][n];
            if (bn_write) {
                // seg1 -> u via bn31 (q=0), seg2 -> avgin via bna1 (q=2)
                const int lc0 = orow - seg * 256;
                const float* ab = (seg == 1) ? (bnab + 0 * 512) : (bnab + 2 * 512);
                unsigned short* dst = (seg == 1) ? u_dst : avg_dst;
                u16x4_t pk;
                #pragma unroll
                for (int j = 0; j < 4; ++j) {
                    float a = ab[lc0 + j], bb = ab[256 + lc0 + j];
                    pk[j] = f2h(a * v[j] + bb);
                }
                *(u16x4_t*)(dst + ((size_t)b * HW + p) * CMID + lc0) = pk;
            } else {
                const int cbase = is_main ? 0 : 256;
                #pragma unroll
                for (int j = 0; j < 4; ++j) {
                    int o = orow + j;
                    int jc = cbase + o;
                    int pos = pos_tab[jc];
                    if (pos >= 0)
                        out[((size_t)b * CFULL + pos) * HW + p] = v[j] * scale_tab[jc];
                }
            }
        }
    }
}

// ---------------------------------------------------------------------------
// Kernel B: mid 3x3 conv (on u) + avgpool+bna2 (on avgin).
//   1-D grid of 6720 blocks, XCD-pinned by batch:
//     xcd = id & 7; slot = id >> 3 (0..839); b = xcd + 8*(slot/420);
//     rem = slot % 420; rem<28 -> mid conv (ob=rem/14, pb=rem%14);
//     else avgpool unit q = rem-28 (0..391), positions q*8..q*8+7.
// ---------------------------------------------------------------------------
__global__ __launch_bounds__(256, 4)
void convB(const unsigned short* __restrict__ U,
           const unsigned short* __restrict__ W33r,
           const unsigned short* __restrict__ avgin,
           const unsigned short* __restrict__ zpad,
           float* __restrict__ out,
           const float* __restrict__ bnab,
           const int* __restrict__ pos_tab,
           const float* __restrict__ scale_tab)
{
    const int id = blockIdx.x;
    const int xcd = id & 7, slot = id >> 3;
    const int b = xcd + 8 * (slot / 420);
    const int rem = slot % 420;

    if (rem < 28) {
        // ---------------- mid 3x3 conv, CIN=256, bn33 + scatter ----------------
        const int ob = rem / 14, pb = rem % 14;
        const int lane = threadIdx.x & 63;
        const int wid  = threadIdx.x >> 6;
        const int wm = wid >> 1, wn = wid & 1;
        const int lr = lane & 15;
        const int ko = (lane >> 4) * 8;
        const int o_wave = ob * 128 + wm * 64;
        const int p_wave = pb * 224 + wn * 112;

        int h_[7], w_[7], p_[7];
        #pragma unroll
        for (int n = 0; n < 7; ++n) {
            int p = p_wave + n * 16 + lr;
            p_[n] = p; h_[n] = p / WDIM; w_[n] = p % WDIM;
        }
        const unsigned short* xb = U + (size_t)b * HW * CMID;

        f32x4_t acc[4][7];
        #pragma unroll
        for (int m = 0; m < 4; ++m)
            #pragma unroll
            for (int n = 0; n < 7; ++n)
                acc[m][n] = (f32x4_t){0.f, 0.f, 0.f, 0.f};

        const unsigned short* ap[4];
        #pragma unroll
        for (int m = 0; m < 4; ++m)
            ap[m] = W33r + (size_t)(o_wave + m * 16 + lr) * (9 * CMID) + ko;

        for (int tap = 0; tap < 9; ++tap) {
            const int dh = tap / 3 - 1, dw = tap % 3 - 1;
            const unsigned short* bp[7];
            #pragma unroll
            for (int n = 0; n < 7; ++n) {
                int hh = h_[n] + dh, ww = w_[n] + dw;
                bool v = ((unsigned)hh < (unsigned)WDIM) && ((unsigned)ww < (unsigned)WDIM);
                bp[n] = v ? (xb + (size_t)(hh * WDIM + ww) * CMID + ko) : zpad;
            }
            #pragma unroll
            for (int kc = 0; kc < CMID / 32; ++kc) {
                f16x8_t af[4], bfr[7];
                #pragma unroll
                for (int m = 0; m < 4; ++m) af[m] = load_h8(ap[m] + kc * 32);
                #pragma unroll
                for (int n = 0; n < 7; ++n) bfr[n] = load_h8(bp[n] + kc * 32);
                #pragma unroll
                for (int m = 0; m < 4; ++m)
                    #pragma unroll
                    for (int n = 0; n < 7; ++n)
                        acc[m][n] = __builtin_amdgcn_mfma_f32_16x16x32_f16(af[m], bfr[n], acc[m][n], 0, 0, 0);
            }
            #pragma unroll
            for (int m = 0; m < 4; ++m) ap[m] += CMID;
        }

        const int fq = lane >> 4;
        const float* ab1 = bnab + 1 * 512;   // bn33
        #pragma unroll
        for (int m = 0; m < 4; ++m) {
            const int orow = o_wave + m * 16 + fq * 4;
            #pragma unroll
            for (int n = 0; n < 7; ++n) {
                const int p = p_[n];
                f32x4_t v = acc[m][n];
                #pragma unroll
                for (int j = 0; j < 4; ++j) {
                    int o = orow + j;
                    float val = ab1[o] * v[j] + ab1[256 + o];
                    int jc = 512 + o;
                    int pos = pos_tab[jc];
                    if (pos >= 0)
                        out[((size_t)b * CFULL + pos) * HW + p] = val * scale_tab[jc];
                }
            }
        }
    } else {
        // ---------------- avgpool 3x3 s1 p1 + bna2 + scatter ----------------
        const int q = rem - 28;
        const int t = threadIdx.x;
        const int p = q * 8 + (t >> 5);
        const int c0 = (t & 31) * 8;
        const int h = p / WDIM, w = p % WDIM;
        const float* ab2 = bnab + 3 * 512;
        float s[8];
        #pragma unroll
        for (int j = 0; j < 8; ++j) s[j] = 0.f;
        #pragma unroll
        for (int dh = -1; dh <= 1; ++dh) {
            int hh = h + dh;
            if ((unsigned)hh >= (unsigned)WDIM) continue;
            #pragma unroll
            for (int dw = -1; dw <= 1; ++dw) {
                int ww = w + dw;
                if ((unsigned)ww >= (unsigned)WDIM) continue;
                u16x8_t v = *(const u16x8_t*)(avgin + ((size_t)b * HW + hh * WDIM + ww) * CMID + c0);
                #pragma unroll
                for (int j = 0; j < 8; ++j) s[j] += h2f(v[j]);
            }
        }
        #pragma unroll
        for (int j = 0; j < 8; ++j) {
            int c = c0 + j;
            int jc = 768 + c;
            int pos = pos_tab[jc];
            if (pos >= 0) {
                float val = (s[j] * (1.f / 9.f)) * ab2[c] + ab2[256 + c];
                out[((size_t)b * CFULL + pos) * HW + p] = val * scale_tab[jc];
            }
        }
    }
}

// ---------------------------------------------------------------------------
// Launch
// ---------------------------------------------------------------------------
extern "C" void kernel_launch(void* const* d_in, const int* in_sizes, int n_in,
                              void* d_out, int out_size, void* d_ws, size_t ws_size,
                              hipStream_t stream) {
    (void)in_sizes; (void)n_in; (void)out_size; (void)ws_size;
    const float* x      = (const float*)d_in[0];
    const float* w_main = (const float*)d_in[1];
    const float* w_1x1  = (const float*)d_in[2];
    const float* w31    = (const float*)d_in[3];
    const float* bn31   = (const float*)d_in[4];
    const float* w33    = (const float*)d_in[5];
    const float* bn33   = (const float*)d_in[6];
    const float* wa1    = (const float*)d_in[7];
    const float* bna1   = (const float*)d_in[8];
    const float* bna2   = (const float*)d_in[9];
    const float* fw     = (const float*)d_in[10];
    const float* cscore = (const float*)d_in[11];
    float* out = (float*)d_out;

    char* ws = (char*)d_ws;
    unsigned short* x_nhwc = (unsigned short*)(ws);                 // 51,380,224 B
    unsigned short* u_nhwc = (unsigned short*)(ws + 51380224);      // 25,690,112 B
    unsigned short* avgin  = (unsigned short*)(ws + 77070336);      // 25,690,112 B
    unsigned short* Wcat   = (unsigned short*)(ws + 102760448);     //    786,432 B
    unsigned short* Wmain  = (unsigned short*)(ws + 103546880);     //  2,359,296 B
    unsigned short* W33r   = (unsigned short*)(ws + 105906176);     //  1,179,648 B
    float*          bnab   = (float*)        (ws + 107085824);      //      8,192 B
    int*            pos_tab= (int*)          (ws + 107094016);      //      4,096 B
    float*          scl_tab= (float*)        (ws + 107098112);      //      4,096 B
    unsigned short* zpad   = (unsigned short*)(ws + 107102208);     //      1,024 B

    dim3 blk(256);

    prep_tabs<<<dim3(1), dim3(1024), 0, stream>>>(cscore, bn31, bn33, bna1, bna2,
                                                  pos_tab, scl_tab, bnab, zpad);
    prep_weights<<<dim3(8448), blk, 0, stream>>>(w_main, w_1x1, w31, wa1, w33, fw,
                                                 Wcat, Wmain, W33r);
    transpose_x<<<dim3(49, 8, 16), blk, 0, stream>>>(x, x_nhwc);

    // Kernel A: main 3x3 + fused 1x1 (XCD-pinned by batch)
    convA<<<dim3(1792), blk, 0, stream>>>(x_nhwc, Wmain, Wcat, zpad, out,
                                          u_nhwc, avgin, bnab, pos_tab, scl_tab);

    // Kernel B: mid 3x3 + avgpool (XCD-pinned by batch)
    convB<<<dim3(6720), blk, 0, stream>>>(u_nhwc, W33r, avgin, zpad, out,
                                          bnab, pos_tab, scl_tab);
}

// Round 3
// 875.811 us; speedup vs baseline: 4.9484x; 4.9484x over previous
//
#include <hip/hip_runtime.h>
#include <hip/hip_bf16.h>
#include <cstdint>
#include <cstddef>

// ---------------------------------------------------------------------------
// Types & helpers
// ---------------------------------------------------------------------------
typedef _Float16 f16x8_t __attribute__((ext_vector_type(8)));
typedef float    f32x4_t __attribute__((ext_vector_type(4)));
typedef unsigned short u16x8_t __attribute__((ext_vector_type(8)));
typedef unsigned short u16x4_t __attribute__((ext_vector_type(4)));

__device__ __forceinline__ unsigned short f2h(float f) {
    return __builtin_bit_cast(unsigned short, (_Float16)f);
}
__device__ __forceinline__ float h2f(unsigned short h) {
    return (float)__builtin_bit_cast(_Float16, h);
}
__device__ __forceinline__ f16x8_t load_h8(const unsigned short* p) {
    u16x8_t r = *(const u16x8_t*)p;
    return __builtin_bit_cast(f16x8_t, r);
}

// ---------------------------------------------------------------------------
// Problem constants
// ---------------------------------------------------------------------------
#define BATCH 16
#define CFULL 512
#define CMID  256
#define HW    3136   // 56*56
#define WDIM  56

// ---------------------------------------------------------------------------
// prep_tabs: top-k ranks + sigmoid scales + BN (a,b) constants + zero pad
//   bnab layout: [4][2][256] floats: q=0 bn31, 1 bn33, 2 bna1, 3 bna2
// ---------------------------------------------------------------------------
__global__ void prep_tabs(const float* __restrict__ cscore,
                          const float* __restrict__ bn31, const float* __restrict__ bn33,
                          const float* __restrict__ bna1, const float* __restrict__ bna2,
                          int* __restrict__ pos_tab, float* __restrict__ scale_tab,
                          float* __restrict__ bnab, unsigned short* __restrict__ zpad)
{
    __shared__ float s[1024];
    int t = threadIdx.x;
    s[t] = cscore[t];
    __syncthreads();
    float sj = s[t];
    int cnt = 0;
    for (int k = 0; k < 1024; ++k) {
        float sk = s[k];
        cnt += (sk > sj) || (sk == sj && k < t);
    }
    pos_tab[t]   = (cnt < 512) ? cnt : -1;
    scale_tab[t] = 1.0f / (1.0f + expf(-sj));

    if (t < 256) {
        const float* srcs[4] = {bn31, bn33, bna1, bna2};
        #pragma unroll
        for (int q = 0; q < 4; ++q) {
            const float* sp = srcs[q];
            float g = sp[t], b = sp[256 + t], m = sp[512 + t], v = sp[768 + t];
            float a = g * rsqrtf(v + 1e-5f);
            bnab[q * 512 + t]       = a;
            bnab[q * 512 + 256 + t] = b - m * a;
        }
    }
    if (t < 512) zpad[t] = 0;
}

// ---------------------------------------------------------------------------
// prep_weights: fp16 weights, fuse_weight folded in.
//   Wcat  [768][512]   rows 0..255 = w_1x1*fw1, 256..511 = w31*fw2, 512..767 = wa1*fw3
//   Wmain [256][9][512]; W33r [256][9][256]
// ---------------------------------------------------------------------------
__global__ void prep_weights(const float* __restrict__ w_main, const float* __restrict__ w_1x1,
                             const float* __restrict__ w31, const float* __restrict__ wa1,
                             const float* __restrict__ w33, const float* __restrict__ fw,
                             unsigned short* __restrict__ Wcat,
                             unsigned short* __restrict__ Wmain,
                             unsigned short* __restrict__ W33r)
{
    int i = blockIdx.x * 256 + threadIdx.x;
    if (i < 393216) {                         // Wcat: 768*512
        int row = i >> 9, c = i & 511;
        float v;
        if (row < 256)      v = w_1x1[row * 512 + c] * fw[1];
        else if (row < 512) v = w31[(row - 256) * 512 + c] * fw[2];
        else                v = wa1[(row - 512) * 512 + c] * fw[3];
        Wcat[i] = f2h(v);
    } else if (i < 393216 + 1179648) {        // Wmain: 256*9*512
        int j = i - 393216;
        int o = j / 4608, r = j % 4608, tap = r >> 9, c = r & 511;
        Wmain[j] = f2h(w_main[(size_t)(o * 512 + c) * 9 + tap] * fw[0]);
    } else if (i < 2162688) {                 // W33r: 256*9*256
        int j = i - 1572864;
        int o = j / 2304, r = j % 2304, tap = r >> 8, c = r & 255;
        W33r[j] = f2h(w33[(size_t)(o * 256 + c) * 9 + tap]);
    }
}

// ---------------------------------------------------------------------------
// transpose_x: NCHW f32 -> NHWC f16.  grid (49, 8, 16), block 256.
// ---------------------------------------------------------------------------
__global__ void transpose_x(const float* __restrict__ x, unsigned short* __restrict__ xt)
{
    __shared__ unsigned short tile[64][65];
    int t = threadIdx.x;
    int hw0 = blockIdx.x * 64, c0 = blockIdx.y * 64, b = blockIdx.z;
    const float* xb = x + ((size_t)b * CFULL + c0) * HW + hw0;
    int hwL = t & 63, cL = t >> 6;
    #pragma unroll
    for (int i = 0; i < 16; ++i) {
        int c = cL + i * 4;
        tile[c][hwL] = f2h(xb[(size_t)c * HW + hwL]);
    }
    __syncthreads();
    int c8 = (t & 7) * 8, hw = t >> 3;
    #pragma unroll
    for (int i = 0; i < 2; ++i) {
        int hh = hw + i * 32;
        u16x8_t v;
        #pragma unroll
        for (int j = 0; j < 8; ++j) v[j] = tile[c8 + j][hh];
        *(u16x8_t*)(xt + ((size_t)b * HW + hw0 + hh) * CFULL + c0 + c8) = v;
    }
}

// ---------------------------------------------------------------------------
// Kernel A: main 3x3 conv + fused 1x1x3 GEMM on x_nhwc.
//   1-D grid of 1792 blocks, XCD-pinned by batch:
//     xcd = id & 7; slot = id >> 3 (0..223); b = xcd + 8*(slot/112);
//     rem = slot % 112; ob = rem/14 (0..7); pb = rem%14.
//   ob 0-1: main 3x3 (256 out ch);  ob 2-7: fused 1x1 (768 out ch).
//   Block tile: 128 out-ch x 224 spatial, 4 waves (2x2), wave 64ch x 112sp.
//   NOTE: __launch_bounds__(256, 2) — NOT 4: the acc[4][7] working set needs
//   ~108 VGPR; capping at 128 (min-waves=4) made the allocator spill acc to
//   scratch (round-2: VGPR=64, 9.9 GB scratch traffic, 3.2 ms). With 108
//   VGPR the HW reaches 4 waves/SIMD on its own.
// ---------------------------------------------------------------------------
__global__ __launch_bounds__(256, 2)
void convA(const unsigned short* __restrict__ X,
           const unsigned short* __restrict__ Wmain,
           const unsigned short* __restrict__ Wcat,
           const unsigned short* __restrict__ zpad,
           float* __restrict__ out,
           unsigned short* __restrict__ u_dst,
           unsigned short* __restrict__ avg_dst,
           const float* __restrict__ bnab,
           const int* __restrict__ pos_tab,
           const float* __restrict__ scale_tab)
{
    const int id = blockIdx.x;
    const int xcd = id & 7, slot = id >> 3;
    const int b = xcd + 8 * (slot / 112);
    const int rem = slot % 112;
    const int ob = rem / 14, pb = rem % 14;
    const bool is_main = (ob < 2);
    const int ntap = is_main ? 9 : 1;
    const int ob2 = ob - 2;                 // fused segment index source

    const int lane = threadIdx.x & 63;
    const int wid  = threadIdx.x >> 6;
    const int wm = wid >> 1, wn = wid & 1;
    const int lr = lane & 15;
    const int ko = (lane >> 4) * 8;

    const int o_wave = (is_main ? ob : ob2) * 128 + wm * 64;
    const int p_wave = pb * 224 + wn * 112;

    int h_[7], w_[7], p_[7];
    #pragma unroll
    for (int n = 0; n < 7; ++n) {
        int p = p_wave + n * 16 + lr;
        p_[n] = p; h_[n] = p / WDIM; w_[n] = p % WDIM;
    }

    const unsigned short* xb = X + (size_t)b * HW * CFULL;

    f32x4_t acc[4][7];
    #pragma unroll
    for (int m = 0; m < 4; ++m)
        #pragma unroll
        for (int n = 0; n < 7; ++n)
            acc[m][n] = (f32x4_t){0.f, 0.f, 0.f, 0.f};

    const int rowstride = ntap * CFULL;
    const unsigned short* wbase = is_main ? Wmain : Wcat;
    const unsigned short* ap[4];
    #pragma unroll
    for (int m = 0; m < 4; ++m)
        ap[m] = wbase + (size_t)(o_wave + m * 16 + lr) * rowstride + ko;

    for (int tap = 0; tap < ntap; ++tap) {
        const int dh = is_main ? (tap / 3 - 1) : 0;
        const int dw = is_main ? (tap % 3 - 1) : 0;
        const unsigned short* bp[7];
        #pragma unroll
        for (int n = 0; n < 7; ++n) {
            int hh = h_[n] + dh, ww = w_[n] + dw;
            bool v = ((unsigned)hh < (unsigned)WDIM) && ((unsigned)ww < (unsigned)WDIM);
            bp[n] = v ? (xb + (size_t)(hh * WDIM + ww) * CFULL + ko) : zpad;
        }
        #pragma unroll 4
        for (int kc = 0; kc < CFULL / 32; ++kc) {
            f16x8_t af[4], bfr[7];
            #pragma unroll
            for (int m = 0; m < 4; ++m) af[m] = load_h8(ap[m] + kc * 32);
            #pragma unroll
            for (int n = 0; n < 7; ++n) bfr[n] = load_h8(bp[n] + kc * 32);
            #pragma unroll
            for (int m = 0; m < 4; ++m)
                #pragma unroll
                for (int n = 0; n < 7; ++n)
                    acc[m][n] = __builtin_amdgcn_mfma_f32_16x16x32_f16(af[m], bfr[n], acc[m][n], 0, 0, 0);
        }
        #pragma unroll
        for (int m = 0; m < 4; ++m) ap[m] += CFULL;
    }

    // ---------------- epilogue ----------------
    const int fq = lane >> 4;
    const int seg = is_main ? 0 : (ob2 >> 1);          // fused: 0,1,2
    const bool bn_write = (!is_main) && (seg != 0);

    #pragma unroll
    for (int m = 0; m < 4; ++m) {
        const int orow = o_wave + m * 16 + fq * 4;
        #pragma unroll
        for (int n = 0; n < 7; ++n) {
            const int p = p_[n];
            f32x4_t v = acc[m][n];
            if (bn_write) {
                // seg1 -> u via bn31 (q=0), seg2 -> avgin via bna1 (q=2)
                const int lc0 = orow - seg * 256;
                const float* ab = (seg == 1) ? (bnab + 0 * 512) : (bnab + 2 * 512);
                unsigned short* dst = (seg == 1) ? u_dst : avg_dst;
                u16x4_t pk;
                #pragma unroll
                for (int j = 0; j < 4; ++j) {
                    float a = ab[lc0 + j], bb = ab[256 + lc0 + j];
                    pk[j] = f2h(a * v[j] + bb);
                }
                *(u16x4_t*)(dst + ((size_t)b * HW + p) * CMID + lc0) = pk;
            } else {
                const int cbase = is_main ? 0 : 256;
                #pragma unroll
                for (int j = 0; j < 4; ++j) {
                    int o = orow + j;
                    int jc = cbase + o;
                    int pos = pos_tab[jc];
                    if (pos >= 0)
                        out[((size_t)b * CFULL + pos) * HW + p] = v[j] * scale_tab[jc];
                }
            }
        }
    }
}

// ---------------------------------------------------------------------------
// Kernel B: mid 3x3 conv (on u) + avgpool+bna2 (on avgin).
//   1-D grid of 6720 blocks, XCD-pinned by batch:
//     xcd = id & 7; slot = id >> 3 (0..839); b = xcd + 8*(slot/420);
//     rem = slot % 420; rem<28 -> mid conv (ob=rem/14, pb=rem%14);
//     else avgpool unit q = rem-28 (0..391), positions q*8..q*8+7.
// ---------------------------------------------------------------------------
__global__ __launch_bounds__(256, 2)
void convB(const unsigned short* __restrict__ U,
           const unsigned short* __restrict__ W33r,
           const unsigned short* __restrict__ avgin,
           const unsigned short* __restrict__ zpad,
           float* __restrict__ out,
           const float* __restrict__ bnab,
           const int* __restrict__ pos_tab,
           const float* __restrict__ scale_tab)
{
    const int id = blockIdx.x;
    const int xcd = id & 7, slot = id >> 3;
    const int b = xcd + 8 * (slot / 420);
    const int rem = slot % 420;

    if (rem < 28) {
        // ---------------- mid 3x3 conv, CIN=256, bn33 + scatter ----------------
        const int ob = rem / 14, pb = rem % 14;
        const int lane = threadIdx.x & 63;
        const int wid  = threadIdx.x >> 6;
        const int wm = wid >> 1, wn = wid & 1;
        const int lr = lane & 15;
        const int ko = (lane >> 4) * 8;
        const int o_wave = ob * 128 + wm * 64;
        const int p_wave = pb * 224 + wn * 112;

        int h_[7], w_[7], p_[7];
        #pragma unroll
        for (int n = 0; n < 7; ++n) {
            int p = p_wave + n * 16 + lr;
            p_[n] = p; h_[n] = p / WDIM; w_[n] = p % WDIM;
        }
        const unsigned short* xb = U + (size_t)b * HW * CMID;

        f32x4_t acc[4][7];
        #pragma unroll
        for (int m = 0; m < 4; ++m)
            #pragma unroll
            for (int n = 0; n < 7; ++n)
                acc[m][n] = (f32x4_t){0.f, 0.f, 0.f, 0.f};

        const unsigned short* ap[4];
        #pragma unroll
        for (int m = 0; m < 4; ++m)
            ap[m] = W33r + (size_t)(o_wave + m * 16 + lr) * (9 * CMID) + ko;

        for (int tap = 0; tap < 9; ++tap) {
            const int dh = tap / 3 - 1, dw = tap % 3 - 1;
            const unsigned short* bp[7];
            #pragma unroll
            for (int n = 0; n < 7; ++n) {
                int hh = h_[n] + dh, ww = w_[n] + dw;
                bool v = ((unsigned)hh < (unsigned)WDIM) && ((unsigned)ww < (unsigned)WDIM);
                bp[n] = v ? (xb + (size_t)(hh * WDIM + ww) * CMID + ko) : zpad;
            }
            #pragma unroll
            for (int kc = 0; kc < CMID / 32; ++kc) {
                f16x8_t af[4], bfr[7];
                #pragma unroll
                for (int m = 0; m < 4; ++m) af[m] = load_h8(ap[m] + kc * 32);
                #pragma unroll
                for (int n = 0; n < 7; ++n) bfr[n] = load_h8(bp[n] + kc * 32);
                #pragma unroll
                for (int m = 0; m < 4; ++m)
                    #pragma unroll
                    for (int n = 0; n < 7; ++n)
                        acc[m][n] = __builtin_amdgcn_mfma_f32_16x16x32_f16(af[m], bfr[n], acc[m][n], 0, 0, 0);
            }
            #pragma unroll
            for (int m = 0; m < 4; ++m) ap[m] += CMID;
        }

        const int fq = lane >> 4;
        const float* ab1 = bnab + 1 * 512;   // bn33
        #pragma unroll
        for (int m = 0; m < 4; ++m) {
            const int orow = o_wave + m * 16 + fq * 4;
            #pragma unroll
            for (int n = 0; n < 7; ++n) {
                const int p = p_[n];
                f32x4_t v = acc[m][n];
                #pragma unroll
                for (int j = 0; j < 4; ++j) {
                    int o = orow + j;
                    float val = ab1[o] * v[j] + ab1[256 + o];
                    int jc = 512 + o;
                    int pos = pos_tab[jc];
                    if (pos >= 0)
                        out[((size_t)b * CFULL + pos) * HW + p] = val * scale_tab[jc];
                }
            }
        }
    } else {
        // ---------------- avgpool 3x3 s1 p1 + bna2 + scatter ----------------
        const int q = rem - 28;
        const int t = threadIdx.x;
        const int p = q * 8 + (t >> 5);
        const int c0 = (t & 31) * 8;
        const int h = p / WDIM, w = p % WDIM;
        const float* ab2 = bnab + 3 * 512;
        float s[8];
        #pragma unroll
        for (int j = 0; j < 8; ++j) s[j] = 0.f;
        #pragma unroll
        for (int dh = -1; dh <= 1; ++dh) {
            int hh = h + dh;
            if ((unsigned)hh >= (unsigned)WDIM) continue;
            #pragma unroll
            for (int dw = -1; dw <= 1; ++dw) {
                int ww = w + dw;
                if ((unsigned)ww >= (unsigned)WDIM) continue;
                u16x8_t v = *(const u16x8_t*)(avgin + ((size_t)b * HW + hh * WDIM + ww) * CMID + c0);
                #pragma unroll
                for (int j = 0; j < 8; ++j) s[j] += h2f(v[j]);
            }
        }
        #pragma unroll
        for (int j = 0; j < 8; ++j) {
            int c = c0 + j;
            int jc = 768 + c;
            int pos = pos_tab[jc];
            if (pos >= 0) {
                float val = (s[j] * (1.f / 9.f)) * ab2[c] + ab2[256 + c];
                out[((size_t)b * CFULL + pos) * HW + p] = val * scale_tab[jc];
            }
        }
    }
}

// ---------------------------------------------------------------------------
// Launch
// ---------------------------------------------------------------------------
extern "C" void kernel_launch(void* const* d_in, const int* in_sizes, int n_in,
                              void* d_out, int out_size, void* d_ws, size_t ws_size,
                              hipStream_t stream) {
    (void)in_sizes; (void)n_in; (void)out_size; (void)ws_size;
    const float* x      = (const float*)d_in[0];
    const float* w_main = (const float*)d_in[1];
    const float* w_1x1  = (const float*)d_in[2];
    const float* w31    = (const float*)d_in[3];
    const float* bn31   = (const float*)d_in[4];
    const float* w33    = (const float*)d_in[5];
    const float* bn33   = (const float*)d_in[6];
    const float* wa1    = (const float*)d_in[7];
    const float* bna1   = (const float*)d_in[8];
    const float* bna2   = (const float*)d_in[9];
    const float* fw     = (const float*)d_in[10];
    const float* cscore = (const float*)d_in[11];
    float* out = (float*)d_out;

    char* ws = (char*)d_ws;
    unsigned short* x_nhwc = (unsigned short*)(ws);                 // 51,380,224 B
    unsigned short* u_nhwc = (unsigned short*)(ws + 51380224);      // 25,690,112 B
    unsigned short* avgin  = (unsigned short*)(ws + 77070336);      // 25,690,112 B
    unsigned short* Wcat   = (unsigned short*)(ws + 102760448);     //    786,432 B
    unsigned short* Wmain  = (unsigned short*)(ws + 103546880);     //  2,359,296 B
    unsigned short* W33r   = (unsigned short*)(ws + 105906176);     //  1,179,648 B
    float*          bnab   = (float*)        (ws + 107085824);      //      8,192 B
    int*            pos_tab= (int*)          (ws + 107094016);      //      4,096 B
    float*          scl_tab= (float*)        (ws + 107098112);      //      4,096 B
    unsigned short* zpad   = (unsigned short*)(ws + 107102208);     //      1,024 B

    dim3 blk(256);

    prep_tabs<<<dim3(1), dim3(1024), 0, stream>>>(cscore, bn31, bn33, bna1, bna2,
                                                  pos_tab, scl_tab, bnab, zpad);
    prep_weights<<<dim3(8448), blk, 0, stream>>>(w_main, w_1x1, w31, wa1, w33, fw,
                                                 Wcat, Wmain, W33r);
    transpose_x<<<dim3(49, 8, 16), blk, 0, stream>>>(x, x_nhwc);

    // Kernel A: main 3x3 + fused 1x1 (XCD-pinned by batch)
    convA<<<dim3(1792), blk, 0, stream>>>(x_nhwc, Wmain, Wcat, zpad, out,
                                          u_nhwc, avgin, bnab, pos_tab, scl_tab);

    // Kernel B: mid 3x3 + avgpool (XCD-pinned by batch)
    convB<<<dim3(6720), blk, 0, stream>>>(u_nhwc, W33r, avgin, zpad, out,
                                          bnab, pos_tab, scl_tab);
}

// Round 4
// 429.379 us; speedup vs baseline: 10.0933x; 2.0397x over previous
//
#include <hip/hip_runtime.h>
#include <hip/hip_bf16.h>
#include <cstdint>
#include <cstddef>

// ---------------------------------------------------------------------------
// Types & helpers
// ---------------------------------------------------------------------------
typedef _Float16 f16x8_t __attribute__((ext_vector_type(8)));
typedef float    f32x4_t __attribute__((ext_vector_type(4)));
typedef unsigned short u16x8_t __attribute__((ext_vector_type(8)));
typedef unsigned short u16x4_t __attribute__((ext_vector_type(4)));

__device__ __forceinline__ unsigned short f2h(float f) {
    return __builtin_bit_cast(unsigned short, (_Float16)f);
}
__device__ __forceinline__ float h2f(unsigned short h) {
    return (float)__builtin_bit_cast(_Float16, h);
}
__device__ __forceinline__ f16x8_t load_h8(const unsigned short* p) {
    u16x8_t r = *(const u16x8_t*)p;
    return __builtin_bit_cast(f16x8_t, r);
}

// ---------------------------------------------------------------------------
// Problem constants
// ---------------------------------------------------------------------------
#define BATCH 16
#define CFULL 512
#define CMID  256
#define HW    3136   // 56*56
#define WDIM  56

// LDS x-tile: 6 rows x 58 cols (1-halo), 32 ch per position, 80B stride
// (64B data + 16B pad -> granule stride 5, coprime with 8 -> no bank conflict)
#define POS_STRIDE_SH 40          // shorts per position (80B)
#define LDS_SHORTS (348 * 40)     // 6*58 positions

// ---------------------------------------------------------------------------
// prep_tabs: top-k ranks + sigmoid scales + BN (a,b) constants
//   bnab layout: [4][2][256] floats: q=0 bn31, 1 bn33, 2 bna1, 3 bna2
// ---------------------------------------------------------------------------
__global__ void prep_tabs(const float* __restrict__ cscore,
                          const float* __restrict__ bn31, const float* __restrict__ bn33,
                          const float* __restrict__ bna1, const float* __restrict__ bna2,
                          int* __restrict__ pos_tab, float* __restrict__ scale_tab,
                          float* __restrict__ bnab)
{
    __shared__ float s[1024];
    int t = threadIdx.x;
    s[t] = cscore[t];
    __syncthreads();
    float sj = s[t];
    int cnt = 0;
    for (int k = 0; k < 1024; ++k) {
        float sk = s[k];
        cnt += (sk > sj) || (sk == sj && k < t);
    }
    pos_tab[t]   = (cnt < 512) ? cnt : -1;
    scale_tab[t] = 1.0f / (1.0f + expf(-sj));

    if (t < 256) {
        const float* srcs[4] = {bn31, bn33, bna1, bna2};
        #pragma unroll
        for (int q = 0; q < 4; ++q) {
            const float* sp = srcs[q];
            float g = sp[t], b = sp[256 + t], m = sp[512 + t], v = sp[768 + t];
            float a = g * rsqrtf(v + 1e-5f);
            bnab[q * 512 + t]       = a;
            bnab[q * 512 + 256 + t] = b - m * a;
        }
    }
}

// ---------------------------------------------------------------------------
// prep_weights: fp16 weights, fuse_weight folded in, MFMA-friendly layout:
//   Wcat2  [16 kch][768 oc][32 ch]   oc 0..255=w_1x1*fw1, 256..511=w31*fw2,
//                                    512..767=wa1*fw3
//   Wmain2 [16 kch][9 tap][256 oc][32 ch] = w_main*fw0
//   W33r2  [ 8 kch][9 tap][256 oc][32 ch] = w33
// ---------------------------------------------------------------------------
__global__ void prep_weights(const float* __restrict__ w_main, const float* __restrict__ w_1x1,
                             const float* __restrict__ w31, const float* __restrict__ wa1,
                             const float* __restrict__ w33, const float* __restrict__ fw,
                             unsigned short* __restrict__ Wcat,
                             unsigned short* __restrict__ Wmain,
                             unsigned short* __restrict__ W33r)
{
    int i = blockIdx.x * 256 + threadIdx.x;
    if (i < 393216) {                         // Wcat: 768*512
        int row = i >> 9, c = i & 511;
        float v;
        if (row < 256)      v = w_1x1[row * 512 + c] * fw[1];
        else if (row < 512) v = w31[(row - 256) * 512 + c] * fw[2];
        else                v = wa1[(row - 512) * 512 + c] * fw[3];
        Wcat[((c >> 5) * 768 + row) * 32 + (c & 31)] = f2h(v);
    } else if (i < 393216 + 1179648) {        // Wmain: 256*9*512
        int j = i - 393216;
        int o = j / 4608, r = j % 4608, tap = r >> 9, c = r & 511;
        Wmain[(((c >> 5) * 9 + tap) * 256 + o) * 32 + (c & 31)] =
            f2h(w_main[(size_t)(o * 512 + c) * 9 + tap] * fw[0]);
    } else if (i < 2162688) {                 // W33r: 256*9*256
        int j = i - 1572864;
        int o = j / 2304, r = j % 2304, tap = r >> 8, c = r & 255;
        W33r[(((c >> 5) * 9 + tap) * 256 + o) * 32 + (c & 31)] =
            f2h(w33[(size_t)(o * 256 + c) * 9 + tap]);
    }
}

// ---------------------------------------------------------------------------
// transpose_x: NCHW f32 -> NHWC f16.  grid (49, 8, 16), block 256.
// ---------------------------------------------------------------------------
__global__ void transpose_x(const float* __restrict__ x, unsigned short* __restrict__ xt)
{
    __shared__ unsigned short tile[64][65];
    int t = threadIdx.x;
    int hw0 = blockIdx.x * 64, c0 = blockIdx.y * 64, b = blockIdx.z;
    const float* xb = x + ((size_t)b * CFULL + c0) * HW + hw0;
    int hwL = t & 63, cL = t >> 6;
    #pragma unroll
    for (int i = 0; i < 16; ++i) {
        int c = cL + i * 4;
        tile[c][hwL] = f2h(xb[(size_t)c * HW + hwL]);
    }
    __syncthreads();
    int c8 = (t & 7) * 8, hw = t >> 3;
    #pragma unroll
    for (int i = 0; i < 2; ++i) {
        int hh = hw + i * 32;
        u16x8_t v;
        #pragma unroll
        for (int j = 0; j < 8; ++j) v[j] = tile[c8 + j][hh];
        *(u16x8_t*)(xt + ((size_t)b * HW + hw0 + hh) * CFULL + c0 + c8) = v;
    }
}

// ---------------------------------------------------------------------------
// conv_body: LDS halo-tile implicit-GEMM conv with tap reuse.
//   Block tile: 128 oc x 224 sp (4 image rows x 56), 4 waves (2 oc x 2 sp),
//   wave 64 oc x 112 sp, acc 4x7. K-chunk = 32 ch; x-tile staged once per
//   K-chunk into LDS (6 rows x 58 cols halo, 80B/pos) and reused by all taps.
//   MODE 0 = main 3x3 -> scatter cbase 0
//   MODE 1 = fused 1x1 -> seg0 scatter cbase 256; seg1 bn31->u; seg2 bna1->avgin
//   MODE 2 = mid 3x3 -> bn33 + scatter cbase 512
// ---------------------------------------------------------------------------
template<int CIN, int NTAP, int MODE>
__device__ __forceinline__ void conv_body(
    const unsigned short* __restrict__ X,
    const unsigned short* __restrict__ Wr,
    float* __restrict__ out,
    unsigned short* __restrict__ u_dst,
    unsigned short* __restrict__ avg_dst,
    const float* __restrict__ bnab,
    const int* __restrict__ pos_tab,
    const float* __restrict__ scale_tab,
    unsigned short* smem, int b, int ob, int pb)
{
    const int t    = threadIdx.x;
    const int lane = t & 63;
    const int wid  = t >> 6;
    const int wm = wid >> 1, wn = wid & 1;
    const int lr = lane & 15;
    const int kq = lane >> 4;              // k-quarter: ko = kq*8 ch
    const int row0 = pb * 4;               // first image row of block tile

    const int o_wave = ob * 128 + wm * 64;
    const int p_wave = pb * 224 + wn * 112;

    // LDS fragment bases at tap corner (-1,-1): tap offset is then
    // ((dh+1)*58 + (dw+1)) * 40 shorts, always non-negative.
    int bofs[7];
    #pragma unroll
    for (int n = 0; n < 7; ++n) {
        int p = p_wave + n * 16 + lr;
        int prow = p / WDIM - row0;        // 0..3
        int pcol = p % WDIM;
        bofs[n] = (prow * 58 + pcol) * POS_STRIDE_SH + kq * 8;
    }

    // zero the whole LDS tile once (halo rows/cols stay zero forever)
    {
        u16x8_t z = (u16x8_t){0, 0, 0, 0, 0, 0, 0, 0};
        #pragma unroll
        for (int i = 0; i < 7; ++i) {
            int j = t + i * 256;
            if (j < LDS_SHORTS / 8) *(u16x8_t*)(smem + j * 8) = z;
        }
    }

    f32x4_t acc[4][7];
    #pragma unroll
    for (int m = 0; m < 4; ++m)
        #pragma unroll
        for (int n = 0; n < 7; ++n)
            acc[m][n] = (f32x4_t){0.f, 0.f, 0.f, 0.f};

    // A fragment bases; layout [kch][tap][OCTOT][32]
    const int astep = (MODE == 1) ? 768 * 32 : 256 * 32;
    const unsigned short* am[4];
    #pragma unroll
    for (int m = 0; m < 4; ++m)
        am[m] = Wr + (size_t)(o_wave + m * 16 + lr) * 32 + kq * 8;

    const unsigned short* xb = X + (size_t)b * HW * CIN;
    const int KCH = CIN / 32;
    const int r_lo = (NTAP == 9) ? 0 : 1;       // staged tile rows [r_lo, r_hi)
    const int nitems = ((NTAP == 9) ? 6 : 4) * 224;

    for (int kch = 0; kch < KCH; ++kch) {
        __syncthreads();
        // ---- stage x-tile chunk: interior cols 1..56, valid rows only ----
        u16x8_t buf[6];
        int dsts[6];
        bool val[6];
        #pragma unroll
        for (int i = 0; i < 6; ++i) {
            int idx = t + i * 256;
            bool act = idx < nitems;
            int r   = r_lo + idx / 224;         // tile row 0..5
            int rm  = idx % 224;
            int col = rm >> 2, sub = rm & 3;    // col 0..55, sub 0..3 (8ch)
            int ir  = row0 + r - 1;             // image row
            bool v  = act && ((unsigned)ir < (unsigned)WDIM);
            if (v) buf[i] = *(const u16x8_t*)(xb + (size_t)(ir * WDIM + col) * CIN
                                              + kch * 32 + sub * 8);
            val[i]  = v;
            dsts[i] = (r * 58 + col + 1) * POS_STRIDE_SH + sub * 8;
        }
        #pragma unroll
        for (int i = 0; i < 6; ++i)
            if (val[i]) *(u16x8_t*)(smem + dsts[i]) = buf[i];
        __syncthreads();

        // ---- compute: all taps reuse the staged tile ----
        #pragma unroll
        for (int tap = 0; tap < NTAP; ++tap) {
            const int dh = (NTAP == 9) ? (tap / 3 - 1) : 0;
            const int dw = (NTAP == 9) ? (tap % 3 - 1) : 0;
            const int toff = ((dh + 1) * 58 + (dw + 1)) * POS_STRIDE_SH;
            f16x8_t af[4];
            #pragma unroll
            for (int m = 0; m < 4; ++m)
                af[m] = load_h8(am[m] + (size_t)(kch * NTAP + tap) * astep);
            f16x8_t bf[7];
            #pragma unroll
            for (int n = 0; n < 7; ++n)
                bf[n] = load_h8(smem + bofs[n] + toff);
            #pragma unroll
            for (int m = 0; m < 4; ++m)
                #pragma unroll
                for (int n = 0; n < 7; ++n)
                    acc[m][n] = __builtin_amdgcn_mfma_f32_16x16x32_f16(af[m], bf[n], acc[m][n], 0, 0, 0);
        }
    }

    // ---------------- epilogue ----------------
    const int fq = lane >> 4;
    const int seg = (MODE == 1) ? (ob >> 1) : 0;
    const bool bn_write = (MODE == 1) && (seg != 0);

    #pragma unroll
    for (int m = 0; m < 4; ++m) {
        const int orow = o_wave + m * 16 + fq * 4;
        #pragma unroll
        for (int n = 0; n < 7; ++n) {
            const int p = p_wave + n * 16 + lr;
            f32x4_t v = acc[m][n];
            if (bn_write) {
                // seg1 -> u via bn31 (q=0), seg2 -> avgin via bna1 (q=2)
                const int lc0 = orow - seg * 256;
                const float* ab = (seg == 1) ? (bnab + 0 * 512) : (bnab + 2 * 512);
                unsigned short* dst = (seg == 1) ? u_dst : avg_dst;
                u16x4_t pk;
                #pragma unroll
                for (int j = 0; j < 4; ++j) {
                    float a = ab[lc0 + j], bb = ab[256 + lc0 + j];
                    pk[j] = f2h(a * v[j] + bb);
                }
                *(u16x4_t*)(dst + ((size_t)b * HW + p) * CMID + lc0) = pk;
            } else {
                const int cbase = (MODE == 0) ? 0 : ((MODE == 2) ? 512 : 256);
                #pragma unroll
                for (int j = 0; j < 4; ++j) {
                    int o = orow + j;
                    float val2 = v[j];
                    if (MODE == 2) val2 = bnab[512 + o] * val2 + bnab[512 + 256 + o];
                    int jc = cbase + o;
                    int pos = pos_tab[jc];
                    if (pos >= 0)
                        out[((size_t)b * CFULL + pos) * HW + p] = val2 * scale_tab[jc];
                }
            }
        }
    }
}

// ---------------------------------------------------------------------------
// Kernel A: main 3x3 (long, scheduled FIRST) + fused 1x1x3 GEMM.
//   1792 blocks. xcd = id&7, slot = id>>3 (0..223):
//     slot <  56 : main 3x3, b = xcd + 8*(slot/28), u = slot%28, ob=u/14, pb=u%14
//     slot >= 56 : fused 1x1, g = slot-56, b = xcd + 8*(g/84), u = g%84,
//                  ob = u/14 (0..5), pb = u%14
// ---------------------------------------------------------------------------
__global__ __launch_bounds__(256, 2)
void convA(const unsigned short* __restrict__ X,
           const unsigned short* __restrict__ Wmain,
           const unsigned short* __restrict__ Wcat,
           float* __restrict__ out,
           unsigned short* __restrict__ u_dst,
           unsigned short* __restrict__ avg_dst,
           const float* __restrict__ bnab,
           const int* __restrict__ pos_tab,
           const float* __restrict__ scale_tab)
{
    __shared__ unsigned short smem[LDS_SHORTS];
    const int id = blockIdx.x;
    const int xcd = id & 7, slot = id >> 3;
    if (slot < 56) {
        const int b = xcd + 8 * (slot / 28);
        const int u = slot % 28;
        conv_body<512, 9, 0>(X, Wmain, out, nullptr, nullptr, bnab,
                             pos_tab, scale_tab, smem, b, u / 14, u % 14);
    } else {
        const int g = slot - 56;
        const int b = xcd + 8 * (g / 84);
        const int u = g % 84;
        conv_body<512, 1, 1>(X, Wcat, out, u_dst, avg_dst, bnab,
                             pos_tab, scale_tab, smem, b, u / 14, u % 14);
    }
}

// ---------------------------------------------------------------------------
// Kernel B: mid 3x3 conv (long, FIRST) + avgpool+bna2.
//   6720 blocks. xcd = id&7, slot = id>>3 (0..839):
//     slot <  56 : mid conv, b = xcd + 8*(slot/28), u = slot%28, ob=u/14, pb=u%14
//     slot >= 56 : pool, g = slot-56, b = xcd + 8*(g/392), q = g%392
// ---------------------------------------------------------------------------
__global__ __launch_bounds__(256, 2)
void convB(const unsigned short* __restrict__ U,
           const unsigned short* __restrict__ W33r,
           const unsigned short* __restrict__ avgin,
           float* __restrict__ out,
           const float* __restrict__ bnab,
           const int* __restrict__ pos_tab,
           const float* __restrict__ scale_tab)
{
    __shared__ unsigned short smem[LDS_SHORTS];
    const int id = blockIdx.x;
    const int xcd = id & 7, slot = id >> 3;
    if (slot < 56) {
        const int b = xcd + 8 * (slot / 28);
        const int u = slot % 28;
        conv_body<256, 9, 2>(U, W33r, out, nullptr, nullptr, bnab,
                             pos_tab, scale_tab, smem, b, u / 14, u % 14);
    } else {
        const int g = slot - 56;
        const int b = xcd + 8 * (g / 392);
        const int q = g % 392;
        const int t = threadIdx.x;
        const int p = q * 8 + (t >> 5);
        const int c0 = (t & 31) * 8;
        const int h = p / WDIM, w = p % WDIM;
        const float* ab2 = bnab + 3 * 512;
        float s[8];
        #pragma unroll
        for (int j = 0; j < 8; ++j) s[j] = 0.f;
        #pragma unroll
        for (int dh = -1; dh <= 1; ++dh) {
            int hh = h + dh;
            if ((unsigned)hh >= (unsigned)WDIM) continue;
            #pragma unroll
            for (int dw = -1; dw <= 1; ++dw) {
                int ww = w + dw;
                if ((unsigned)ww >= (unsigned)WDIM) continue;
                u16x8_t v = *(const u16x8_t*)(avgin + ((size_t)b * HW + hh * WDIM + ww) * CMID + c0);
                #pragma unroll
                for (int j = 0; j < 8; ++j) s[j] += h2f(v[j]);
            }
        }
        #pragma unroll
        for (int j = 0; j < 8; ++j) {
            int c = c0 + j;
            int jc = 768 + c;
            int pos = pos_tab[jc];
            if (pos >= 0) {
                float val = (s[j] * (1.f / 9.f)) * ab2[c] + ab2[256 + c];
                out[((size_t)b * CFULL + pos) * HW + p] = val * scale_tab[jc];
            }
        }
    }
}

// ---------------------------------------------------------------------------
// Launch
// ---------------------------------------------------------------------------
extern "C" void kernel_launch(void* const* d_in, const int* in_sizes, int n_in,
                              void* d_out, int out_size, void* d_ws, size_t ws_size,
                              hipStream_t stream) {
    (void)in_sizes; (void)n_in; (void)out_size; (void)ws_size;
    const float* x      = (const float*)d_in[0];
    const float* w_main = (const float*)d_in[1];
    const float* w_1x1  = (const float*)d_in[2];
    const float* w31    = (const float*)d_in[3];
    const float* bn31   = (const float*)d_in[4];
    const float* w33    = (const float*)d_in[5];
    const float* bn33   = (const float*)d_in[6];
    const float* wa1    = (const float*)d_in[7];
    const float* bna1   = (const float*)d_in[8];
    const float* bna2   = (const float*)d_in[9];
    const float* fw     = (const float*)d_in[10];
    const float* cscore = (const float*)d_in[11];
    float* out = (float*)d_out;

    char* ws = (char*)d_ws;
    unsigned short* x_nhwc = (unsigned short*)(ws);                 // 51,380,224 B
    unsigned short* u_nhwc = (unsigned short*)(ws + 51380224);      // 25,690,112 B
    unsigned short* avgin  = (unsigned short*)(ws + 77070336);      // 25,690,112 B
    unsigned short* Wcat   = (unsigned short*)(ws + 102760448);     //    786,432 B
    unsigned short* Wmain  = (unsigned short*)(ws + 103546880);     //  2,359,296 B
    unsigned short* W33r   = (unsigned short*)(ws + 105906176);     //  1,179,648 B
    float*          bnab   = (float*)        (ws + 107085824);      //      8,192 B
    int*            pos_tab= (int*)          (ws + 107094016);      //      4,096 B
    float*          scl_tab= (float*)        (ws + 107098112);      //      4,096 B

    dim3 blk(256);

    prep_tabs<<<dim3(1), dim3(1024), 0, stream>>>(cscore, bn31, bn33, bna1, bna2,
                                                  pos_tab, scl_tab, bnab);
    prep_weights<<<dim3(8448), blk, 0, stream>>>(w_main, w_1x1, w31, wa1, w33, fw,
                                                 Wcat, Wmain, W33r);
    transpose_x<<<dim3(49, 8, 16), blk, 0, stream>>>(x, x_nhwc);

    // Kernel A: main 3x3 (first) + fused 1x1 (XCD-pinned by batch)
    convA<<<dim3(1792), blk, 0, stream>>>(x_nhwc, Wmain, Wcat, out,
                                          u_nhwc, avgin, bnab, pos_tab, scl_tab);

    // Kernel B: mid 3x3 (first) + avgpool (XCD-pinned by batch)
    convB<<<dim3(6720), blk, 0, stream>>>(u_nhwc, W33r, avgin, out,
                                          bnab, pos_tab, scl_tab);
}